// Round 3
// baseline (1463008.105 us; speedup 1.0000x reference)
//
#include <hip/hip_runtime.h>
#include <math.h>

typedef __attribute__((ext_vector_type(8))) short short8;
typedef __attribute__((ext_vector_type(4))) float floatx4;
typedef __attribute__((ext_vector_type(4))) unsigned int uintx4;
typedef unsigned short ushort_t;
typedef unsigned int uint_t;
typedef unsigned long long ull_t;

// Problem constants
constexpr int C_B   = 512;
constexpr int C_T   = 365;
constexpr int C_IN  = 10;
constexpr int C_H   = 256;
constexpr int C_OUT = 20;

// 192 blocks: 16 strips x 12 roles (4 L0 + 8 L1). Block->strip mapping keeps
// all 12 roles of a strip on one XCD under round-robin (bid%8) placement.
constexpr int NB  = 192;

// Workspace layout (ushort units for weight planes):
// B planes: mat(3: Whh0,Wih1,Whh1) x plane(hi,lo) x [48 nt][8 ks][64 lane][8]
constexpr size_t PLANE_U = 48ull * 8 * 64 * 8;   // 196608 ushorts
constexpr size_t US_H    = 6 * PLANE_U;          // ushort offset of packed-h region
// h planes: packed uint32 (hi<<16 | lo), plane idx = which(0=h0,1=h1)*2 + parity
constexpr size_t HP_SZU  = 512ull * 256;         // uints per h plane
// sync area (uints, after 4 h planes), 128B-padded per strip:
//   cnt[mt]  @ SY + mt*32        (main step flags)
//   rdy[mt]  @ SY + 512 + mt*32  (handshake ready counters)
//   xct[mt,r]@ SY + 1024 + mt*32 + r   (XCC id exchange)
constexpr int SY_TOT = 2048;
constexpr unsigned STRIP = 12;
constexpr unsigned SPIN_MAIN = 1u << 15;   // valve: terminate visibly, never hang
constexpr unsigned SPIN_HAND = 1u << 16;

__device__ __forceinline__ float fsig(float v)  { return 1.0f / (1.0f + __expf(-v)); }
__device__ __forceinline__ float ftanh(float v) { return 2.0f / (1.0f + __expf(-2.0f * v)) - 1.0f; }

__device__ __forceinline__ void split1(float x, ushort_t& hi, ushort_t& lo) {
    unsigned u = __float_as_uint(x);
    hi = (ushort_t)(u >> 16);
    float r = x - __uint_as_float(u & 0xffff0000u);
    lo = (ushort_t)(__float_as_uint(r) >> 16);
}

// packed h element: top 16 bits = bf16(hi), low 16 bits = bf16(residual)
__device__ __forceinline__ uint_t packsplit(float x) {
    unsigned u = __float_as_uint(x);
    unsigned hib = u & 0xffff0000u;
    float r = x - __uint_as_float(hib);
    return hib | (__float_as_uint(r) >> 16);
}

__device__ __forceinline__ float lds_h(const ushort_t* hi, const ushort_t* lo, int idx) {
    return __uint_as_float(((unsigned)hi[idx]) << 16) + __uint_as_float(((unsigned)lo[idx]) << 16);
}

// ---------------- weight pre-pack (+ sync-area zeroing) ----------------
__global__ __launch_bounds__(256) void prep_pack(const float* __restrict__ Whh0,
                                                 const float* __restrict__ Wih1,
                                                 const float* __restrict__ Whh1,
                                                 ushort_t* __restrict__ PW) {
    const int blk = blockIdx.x;            // 144 = mat(3) x g(3) x jb(16)
    const int tid = threadIdx.x;

    // zero flags + handshake tables each launch (kills cross-run staleness)
    if (blk == 0) {
        uint_t* SY = (uint_t*)(PW + US_H) + 4 * HP_SZU;
        for (int u = tid; u < SY_TOT; u += 256)
            __hip_atomic_store(SY + u, 0u, __ATOMIC_RELAXED, __HIP_MEMORY_SCOPE_AGENT);
    }

    const int mat = blk / 48;
    const int rem = blk % 48;
    const int g   = rem / 16;
    const int jb  = rem % 16;
    const float* S = (mat == 0) ? Whh0 : (mat == 1) ? Wih1 : Whh1;

    const int jl  = tid >> 4;
    const int kc  = tid & 15;
    const int j   = jb * 16 + jl;
    const int nt  = jb * 3 + g;

    const float* src = S + (g * 256 + j) * 256 + kc * 16;
    float f[16];
#pragma unroll
    for (int q = 0; q < 4; q++) {
        float4 v = *(const float4*)(src + q * 4);
        f[q*4+0] = v.x; f[q*4+1] = v.y; f[q*4+2] = v.z; f[q*4+3] = v.w;
    }
    ushort_t hi[16], lo[16];
#pragma unroll
    for (int e = 0; e < 16; e++) split1(f[e], hi[e], lo[e]);

    ushort_t* dhi = PW + (size_t)(mat * 2 + 0) * PLANE_U;
    ushort_t* dlo = PW + (size_t)(mat * 2 + 1) * PLANE_U;
    const int ks = kc >> 1;
#pragma unroll
    for (int hh = 0; hh < 2; hh++) {
        const int quad = (kc & 1) * 2 + hh;
        const int L    = quad * 16 + jl;
        const size_t base = ((size_t)(nt * 8 + ks)) * 512 + L * 8;
        short8 vh, vl;
#pragma unroll
        for (int e = 0; e < 8; e++) { vh[e] = (short)hi[hh*8+e]; vl[e] = (short)lo[hh*8+e]; }
        *(short8*)(dhi + base) = vh;
        *(short8*)(dlo + base) = vl;
    }
}

// ---------------- staging: batch-issue 16B loads, then commit to LDS ----------------
// FAST: sc0 (L1-bypass) loads hit the XCD-shared L2 where producers' plain
//       write-back stores land. SLOW: device-scope intrinsic loads (round-1-proven).
template<bool FAST>
__device__ __forceinline__ void stage_issue(const uint_t* __restrict__ g, uintx4 (&v)[8], int tid) {
    const int c0 = (tid & 63) * 4;
    const int r0 = tid >> 6;
#pragma unroll
    for (int rr = 0; rr < 8; rr++) {
        const uint_t* p = g + (r0 + rr * 4) * 256 + c0;
        if (FAST) {
            asm volatile("global_load_dwordx4 %0, %1, off sc0"
                         : "=v"(v[rr]) : "v"(p));
        } else {
            ull_t q0 = __hip_atomic_load((const ull_t*)(p),
                                         __ATOMIC_RELAXED, __HIP_MEMORY_SCOPE_AGENT);
            ull_t q1 = __hip_atomic_load((const ull_t*)(p + 2),
                                         __ATOMIC_RELAXED, __HIP_MEMORY_SCOPE_AGENT);
            v[rr][0] = (uint_t)q0; v[rr][1] = (uint_t)(q0 >> 32);
            v[rr][2] = (uint_t)q1; v[rr][3] = (uint_t)(q1 >> 32);
        }
    }
    if (FAST) {
        asm volatile("s_waitcnt vmcnt(0)" ::: "memory");
        __builtin_amdgcn_sched_barrier(0);
    }
}

__device__ __forceinline__ void stage_commit(const uintx4 (&v)[8], ushort_t* s_hi, ushort_t* s_lo, int tid) {
    const int c0 = (tid & 63) * 4;
    const int r0 = tid >> 6;
#pragma unroll
    for (int rr = 0; rr < 8; rr++) {
        const int row = r0 + rr * 4;
        const uint_t u0 = v[rr][0], u1 = v[rr][1], u2 = v[rr][2], u3 = v[rr][3];
        uint2 hv, lv;
        hv.x = (u0 >> 16) | (u1 & 0xffff0000u);
        hv.y = (u2 >> 16) | (u3 & 0xffff0000u);
        lv.x = (u0 & 0xffffu) | (u1 << 16);
        lv.y = (u2 & 0xffffu) | (u3 << 16);
        *(uint2*)(s_hi + row * 264 + c0) = hv;
        *(uint2*)(s_lo + row * 264 + c0) = lv;
    }
}

template<bool FAST>
__device__ __forceinline__ void st_h(uint_t* p, uint_t val) {
    if (FAST) {
        *p = val;   // write-back: lands in this XCD's L2 (L1 is write-through)
    } else {
        __hip_atomic_store(p, val, __ATOMIC_RELAXED, __HIP_MEMORY_SCOPE_AGENT);
    }
}

template<bool FAST>
__device__ __forceinline__ uint_t ld_flag(const uint_t* p) {
    if (FAST) {
        uint_t v;
        asm volatile("global_load_dword %0, %1, off sc0\n\ts_waitcnt vmcnt(0)"
                     : "=v"(v) : "v"(p) : "memory");
        return v;
    }
    return __hip_atomic_load(p, __ATOMIC_RELAXED, __HIP_MEMORY_SCOPE_AGENT);
}

// Called by tid 0 AFTER __syncthreads(): every wave in the block has already
// drained its stores (compiler emits vmcnt(0) before s_barrier), so a RELAXED
// add suffices — no release fence, no buffer_wbl2 L2 walk (round-1's killer).
template<bool FAST>
__device__ __forceinline__ void publish(uint_t* cme) {
    if (FAST) {
        uint_t one = 1u;
        asm volatile("global_atomic_add %0, %1, off" :: "v"(cme), "v"(one) : "memory");
    } else {
        __hip_atomic_fetch_add(cme, 1u, __ATOMIC_RELAXED, __HIP_MEMORY_SCOPE_AGENT);
    }
}

// 3 N-tiles x full K=256, 3-pass split-bf16, two M-tiles sharing B regs.
__device__ __forceinline__ void wave_gemm(const ushort_t* sh_hi, const ushort_t* sh_lo,
                                          const ushort_t* __restrict__ bh_base,
                                          const ushort_t* __restrict__ bl_base,
                                          int jbg, int lane, floatx4 acc[3][2]) {
    const int m = lane & 15, quad = lane >> 4;
    const int aoff = m * 264 + quad * 8;
#pragma unroll
    for (int ks = 0; ks < 8; ks++) {
        short8 a0h = *(const short8*)(sh_hi + aoff + ks * 32);
        short8 a0l = *(const short8*)(sh_lo + aoff + ks * 32);
        short8 a1h = *(const short8*)(sh_hi + aoff + 16 * 264 + ks * 32);
        short8 a1l = *(const short8*)(sh_lo + aoff + 16 * 264 + ks * 32);
#pragma unroll
        for (int g = 0; g < 3; g++) {
            const size_t boff = (size_t)(jbg * 3 + g) * 4096 + (size_t)ks * 512 + lane * 8;
            short8 bh = *(const short8*)(bh_base + boff);
            short8 bl = *(const short8*)(bl_base + boff);
            acc[g][0] = __builtin_amdgcn_mfma_f32_16x16x32_bf16(a0h, bh, acc[g][0], 0, 0, 0);
            acc[g][0] = __builtin_amdgcn_mfma_f32_16x16x32_bf16(a0l, bh, acc[g][0], 0, 0, 0);
            acc[g][0] = __builtin_amdgcn_mfma_f32_16x16x32_bf16(a0h, bl, acc[g][0], 0, 0, 0);
            acc[g][1] = __builtin_amdgcn_mfma_f32_16x16x32_bf16(a1h, bh, acc[g][1], 0, 0, 0);
            acc[g][1] = __builtin_amdgcn_mfma_f32_16x16x32_bf16(a1l, bh, acc[g][1], 0, 0, 0);
            acc[g][1] = __builtin_amdgcn_mfma_f32_16x16x32_bf16(a1h, bl, acc[g][1], 0, 0, 0);
        }
    }
}

// ---------------- the persistent T-loop (templated on coherence mode) ----------------
template<bool FAST>
__device__ __forceinline__ void gru_loop(
    const float* __restrict__ x,
    const float* __restrict__ Wih0,
    const float* __restrict__ bih0, const float* __restrict__ bhh0,
    const float* __restrict__ bih1, const float* __restrict__ bhh1,
    ushort_t* __restrict__ WS,
    int mt, int ng, bool isL0, int tid,
    ushort_t* shA_hi, ushort_t* shA_lo, ushort_t* shB_hi, ushort_t* shB_lo,
    float (*xs)[C_IN], float (*ldH)[3][32][17])
{
    const int lane = tid & 63;
    const int w    = tid >> 6;
    const int jlo  = lane & 15;
    const int quad = lane >> 4;
    const int b0   = mt * 32;

    uint_t* const hU  = (uint_t*)(WS + US_H);
    uint_t* const cme = hU + 4 * HP_SZU + mt * 32;

    const int jbg0  = ng * 4 + w;        // L0 wave's jbg
    const int mat   = w >> 1;            // L1: 0 = Wih1 x h0, 1 = Whh1 x h1
    const int jbsub = w & 1;
    const int jbg1  = ng * 2 + jbsub;

    // ---- loop-invariant hoists ----
    float wxr[C_IN], wxz[C_IN], wxn[C_IN];
    float b_r = 0.f, b_z = 0.f, b_in = 0.f, b_hn = 0.f;
    if (isL0) {
        const int j = jbg0 * 16 + jlo;
#pragma unroll
        for (int i = 0; i < C_IN; i++) {
            wxr[i] = Wih0[j * C_IN + i];
            wxz[i] = Wih0[(256 + j) * C_IN + i];
            wxn[i] = Wih0[(512 + j) * C_IN + i];
        }
        b_r  = bih0[j] + bhh0[j];
        b_z  = bih0[256 + j] + bhh0[256 + j];
        b_in = bih0[512 + j];
        b_hn = bhh0[512 + j];
    } else if (mat == 0) {
        const int j = jbg1 * 16 + jlo;
        b_r  = bih1[j] + bhh1[j];
        b_z  = bih1[256 + j] + bhh1[256 + j];
        b_in = bih1[512 + j];
        b_hn = bhh1[512 + j];
    }
    const int rA = tid / C_IN, cA = tid - rA * C_IN;
    const int uB = tid + 256;
    const int rB = uB / C_IN, cB = uB - rB * C_IN;
    const int xoffA = (b0 + rA) * (C_T * C_IN) + cA;
    const int xoffB = (b0 + rB) * (C_T * C_IN) + cB;

#pragma unroll 1
    for (int k = 0; k <= C_T; ++k) {
        const int srcp = (k + 1) & 1, dstp = k & 1;
        const bool do_l0 = isL0 && (k < C_T);
        const bool l0z   = (k == 0);
        const bool do_l1 = (!isL0) && (k >= 1);
        const bool l1z   = (k == 1);

        // x prefetch (read-only input, normal cached load; in flight across the spin)
        float xa = 0.f, xb = 0.f;
        if (do_l0) {
            xa = x[xoffA + k * C_IN];
            if (tid < 64) xb = x[xoffB + k * C_IN];
        }

        // per-wave spin (all lanes poll same address -> 1 coalesced txn/wave)
        if (k > 0) {
            const uint_t tgt = STRIP * (uint_t)k;
            uint_t it = 0;
            for (;;) {
                uint_t v = ld_flag<FAST>(cme);
                if (v >= tgt) break;
                if (++it > SPIN_MAIN) break;   // valve: wrong-but-terminating, never hangs
                if (FAST) asm volatile("s_sleep 1");
                else      asm volatile("s_sleep 4");
            }
        }

        if (isL0) {
            if (do_l0) {
                xs[rA][cA] = xa;
                if (tid < 64) xs[rB][cB] = xb;
                if (!l0z) {
                    uintx4 va[8];
                    const uint_t* h0sb = hU + (size_t)srcp * HP_SZU + b0 * 256;
                    stage_issue<FAST>(h0sb, va, tid);
                    stage_commit(va, shA_hi, shA_lo, tid);
                }
                __syncthreads();

                floatx4 acc[3][2];
#pragma unroll
                for (int g = 0; g < 3; g++) { acc[g][0] = (floatx4){0,0,0,0}; acc[g][1] = (floatx4){0,0,0,0}; }
                if (!l0z)
                    wave_gemm(shA_hi, shA_lo, WS, WS + PLANE_U, jbg0, lane, acc);

                uint_t* const h0d = hU + (size_t)dstp * HP_SZU;
                const int j = jbg0 * 16 + jlo;
#pragma unroll
                for (int m = 0; m < 2; m++) {
#pragma unroll
                    for (int r = 0; r < 4; r++) {
                        const int row = m * 16 + quad * 4 + r;
                        float xrv = 0.f, xzv = 0.f, xnv = 0.f;
#pragma unroll
                        for (int i = 0; i < C_IN; i++) {
                            const float xv = xs[row][i];
                            xrv += xv * wxr[i]; xzv += xv * wxz[i]; xnv += xv * wxn[i];
                        }
                        const int gi = (b0 + row) * C_H + j;
                        // h_prev from the staged LDS tile (identical hi+lo reconstruction)
                        const float hp = l0z ? 0.f : lds_h(shA_hi, shA_lo, row * 264 + j);
                        const float ar  = acc[0][m][r] + xrv + b_r;
                        const float az  = acc[1][m][r] + xzv + b_z;
                        const float inn = xnv + b_in;
                        const float hn  = acc[2][m][r] + b_hn;
                        const float rg = fsig(ar), zg = fsig(az);
                        const float nn = ftanh(inn + rg * hn);
                        st_h<FAST>(h0d + gi, packsplit(zg * (hp - nn) + nn));
                    }
                }
            }
        } else {
            if (do_l1) {
                uintx4 va[8], vb[8];
                const uint_t* h0sb = hU + (size_t)srcp * HP_SZU + b0 * 256;
                const uint_t* h1sb = hU + (size_t)(2 + srcp) * HP_SZU + b0 * 256;
                stage_issue<FAST>(h0sb, va, tid);
                stage_commit(va, shA_hi, shA_lo, tid);
                if (!l1z) {
                    stage_issue<FAST>(h1sb, vb, tid);
                    stage_commit(vb, shB_hi, shB_lo, tid);
                }
                __syncthreads();

                floatx4 acc[3][2];
#pragma unroll
                for (int g = 0; g < 3; g++) { acc[g][0] = (floatx4){0,0,0,0}; acc[g][1] = (floatx4){0,0,0,0}; }
                if (mat == 0)
                    wave_gemm(shA_hi, shA_lo, WS + 2 * PLANE_U, WS + 3 * PLANE_U, jbg1, lane, acc);
                else if (!l1z)
                    wave_gemm(shB_hi, shB_lo, WS + 4 * PLANE_U, WS + 5 * PLANE_U, jbg1, lane, acc);

                if (mat == 1) {
#pragma unroll
                    for (int g = 0; g < 3; g++)
#pragma unroll
                        for (int m = 0; m < 2; m++)
#pragma unroll
                            for (int r = 0; r < 4; r++)
                                ldH[jbsub][g][m * 16 + quad * 4 + r][jlo] = acc[g][m][r];
                }
                __syncthreads();

                if (mat == 0) {
                    const int j = jbg1 * 16 + jlo;
                    uint_t* const h1d = hU + (size_t)(2 + dstp) * HP_SZU;
#pragma unroll
                    for (int m = 0; m < 2; m++) {
#pragma unroll
                        for (int r = 0; r < 4; r++) {
                            const int row = m * 16 + quad * 4 + r;
                            const int gi = (b0 + row) * C_H + j;
                            const float hp = l1z ? 0.f : lds_h(shB_hi, shB_lo, row * 264 + j);
                            const float ar  = acc[0][m][r] + ldH[jbsub][0][row][jlo] + b_r;
                            const float az  = acc[1][m][r] + ldH[jbsub][1][row][jlo] + b_z;
                            const float inn = acc[2][m][r] + b_in;
                            const float hn  = ldH[jbsub][2][row][jlo] + b_hn;
                            const float rg = fsig(ar), zg = fsig(az);
                            const float nn = ftanh(inn + rg * hn);
                            st_h<FAST>(h1d + gi, packsplit(zg * (hp - nn) + nn));
                        }
                    }
                }
            }
        }

        // barrier drains all waves' stores (compiler emits vmcnt(0) before
        // s_barrier); then one relaxed atomic add publishes the step.
        __syncthreads();
        if (tid == 0) publish<FAST>(cme);
    }
}

__global__ __launch_bounds__(256) void gru_persistent(
    const float* __restrict__ x,
    const float* __restrict__ Wih0,
    const float* __restrict__ bih0, const float* __restrict__ bhh0,
    const float* __restrict__ bih1, const float* __restrict__ bhh1,
    ushort_t* __restrict__ WS)
{
    __shared__ __align__(16) ushort_t shA_hi[32 * 264], shA_lo[32 * 264];
    __shared__ __align__(16) ushort_t shB_hi[32 * 264], shB_lo[32 * 264];
    __shared__ float xs[32][C_IN];
    __shared__ float ldH[2][3][32][17];
    __shared__ int fastFlag;

    const int tid = threadIdx.x;
    const int bid = blockIdx.x;
    // strip-major mapping: all 12 blocks of strip mt share bid%8 (same XCD
    // under round-robin placement). Verified at runtime below; never assumed.
    const int slot = bid >> 3;                 // 0..23
    const int mt   = (bid & 7) + ((slot >= 12) ? 8 : 0);
    const int role = (slot >= 12) ? slot - 12 : slot;   // 0..11
    const bool isL0 = role < 4;
    const int ng = isL0 ? role : role - 4;

    uint_t* const hU  = (uint_t*)(WS + US_H);
    uint_t* const SY  = hU + 4 * HP_SZU;
    uint_t* const rdy = SY + 512 + mt * 32;
    uint_t* const xct = SY + 1024 + mt * 32;

    // ---- runtime coherence handshake (device-scope intrinsics only).
    // All 12 blocks read the SAME sc1 data -> all compute the SAME verdict:
    // mixed FAST/SLOW within a strip is impossible by construction.
    if (tid == 0) {
        uint_t xcc;
        asm volatile("s_getreg_b32 %0, hwreg(HW_REG_XCC_ID)" : "=s"(xcc));
        __hip_atomic_store(xct + role, xcc | 0x100u, __ATOMIC_RELAXED, __HIP_MEMORY_SCOPE_AGENT);
        // RELEASE: xct store globally visible before rdy increment (once per block)
        __hip_atomic_fetch_add(rdy, 1u, __ATOMIC_RELEASE, __HIP_MEMORY_SCOPE_AGENT);
        uint_t it = 0;
        while (__hip_atomic_load(rdy, __ATOMIC_RELAXED, __HIP_MEMORY_SCOPE_AGENT) < STRIP) {
            if (++it > SPIN_HAND) break;
            asm volatile("s_sleep 16");
        }
        int ok = 1;
        const uint_t me = xcc | 0x100u;
        for (int r2 = 0; r2 < 12; r2++) {
            uint_t v = __hip_atomic_load(xct + r2, __ATOMIC_RELAXED, __HIP_MEMORY_SCOPE_AGENT);
            if (v != me) ok = 0;   // unset (0) or different XCD -> fallback
        }
        fastFlag = ok;
    }
    __syncthreads();
    const bool fast = (fastFlag != 0);

    if (fast)
        gru_loop<true >(x, Wih0, bih0, bhh0, bih1, bhh1, WS, mt, ng, isL0, tid,
                        shA_hi, shA_lo, shB_hi, shB_lo, xs, ldH);
    else
        gru_loop<false>(x, Wih0, bih0, bhh0, bih1, bhh1, WS, mt, ng, isL0, tid,
                        shA_hi, shA_lo, shB_hi, shB_lo, xs, ldH);
}

__global__ __launch_bounds__(256) void classifier_kernel(
    const ushort_t* __restrict__ WS,
    const float* __restrict__ Wout, const float* __restrict__ bout,
    float* __restrict__ out)
{
    __shared__ float hs[32][C_H + 4];
    __shared__ float lg[32 * C_OUT];
    const int tid = threadIdx.x;
    const int b0  = blockIdx.x * 32;
    // final h1 written at k=365 -> parity 1 -> plane index 2+1 = 3
    // (cross-dispatch visibility: runtime flushes/invalidates caches between
    //  stream-ordered kernels)
    const uint_t* hp1 = (const uint_t*)(WS + US_H) + 3 * HP_SZU;
#pragma unroll
    for (int i = 0; i < 32; i++) {
        uint_t u = hp1[(b0 + i) * C_H + tid];
        hs[i][tid] = __uint_as_float(u & 0xffff0000u) + __uint_as_float(u << 16);
    }
    __syncthreads();
    for (int u = tid; u < 32 * C_OUT; u += 256) {
        int bb = u / C_OUT, o = u - bb * C_OUT;
        const float* wr = Wout + o * C_H;
        float acc = bout[o];
#pragma unroll 4
        for (int k = 0; k < C_H; k += 4) {
            float4 wv = *(const float4*)(wr + k);
            float4 hv = *(const float4*)(&hs[bb][k]);
            acc += wv.x*hv.x + wv.y*hv.y + wv.z*hv.z + wv.w*hv.w;
        }
        lg[u] = acc;
    }
    __syncthreads();
    if (tid < 32) {
        float mx = -1e30f;
#pragma unroll
        for (int o = 0; o < C_OUT; o++) mx = fmaxf(mx, lg[tid * C_OUT + o]);
        float e[C_OUT];
        float s = 0.0f;
#pragma unroll
        for (int o = 0; o < C_OUT; o++) { e[o] = __expf(lg[tid * C_OUT + o] - mx); s += e[o]; }
        float inv = 1.0f / s;
#pragma unroll
        for (int o = 0; o < C_OUT; o++) out[(b0 + tid) * C_OUT + o] = e[o] * inv;
    }
}

extern "C" void kernel_launch(void* const* d_in, const int* in_sizes, int n_in,
                              void* d_out, int out_size, void* d_ws, size_t ws_size,
                              hipStream_t stream) {
    const float* x    = (const float*)d_in[0];
    // d_in[1] = times (unused), d_in[2] = interpolation_method (unused)
    const float* Wih0 = (const float*)d_in[3];
    const float* Whh0 = (const float*)d_in[4];
    const float* bih0 = (const float*)d_in[5];
    const float* bhh0 = (const float*)d_in[6];
    const float* Wih1 = (const float*)d_in[7];
    const float* Whh1 = (const float*)d_in[8];
    const float* bih1 = (const float*)d_in[9];
    const float* bhh1 = (const float*)d_in[10];
    const float* Wout = (const float*)d_in[11];
    const float* bout = (const float*)d_in[12];
    float* out = (float*)d_out;
    ushort_t* WS = (ushort_t*)d_ws;

    // pack weights + zero sync area
    prep_pack<<<144, 256, 0, stream>>>(Whh0, Wih1, Whh1, WS);
    // whole recurrence in ONE dispatch (replaces 366 launches)
    gru_persistent<<<NB, 256, 0, stream>>>(x, Wih0, bih0, bhh0, bih1, bhh1, WS);
    classifier_kernel<<<C_B / 32, 256, 0, stream>>>(WS, Wout, bout, out);
}

// Round 4
// 2843.445 us; speedup vs baseline: 514.5196x; 514.5196x over previous
//
#include <hip/hip_runtime.h>
#include <math.h>

typedef __attribute__((ext_vector_type(8))) short short8;
typedef __attribute__((ext_vector_type(4))) float floatx4;
typedef __attribute__((ext_vector_type(4))) unsigned int uintx4;
typedef unsigned short ushort_t;
typedef unsigned int uint_t;
typedef unsigned long long ull_t;

// Problem constants
constexpr int C_B   = 512;
constexpr int C_T   = 365;
constexpr int C_IN  = 10;
constexpr int C_H   = 256;
constexpr int C_OUT = 20;

// 192 blocks: 16 strips x 12 roles (4 L0 + 8 L1). Block->strip mapping keeps
// all 12 roles of a strip on one XCD under round-robin (bid%8) placement —
// CONFIRMED by round-3 run (handshake returned FAST everywhere).
constexpr int NB  = 192;

// Workspace layout (ushort units for weight planes):
// B planes: mat(3: Whh0,Wih1,Whh1) x plane(hi,lo) x [48 nt][8 ks][64 lane][8]
constexpr size_t PLANE_U = 48ull * 8 * 64 * 8;   // 196608 ushorts
constexpr size_t US_H    = 6 * PLANE_U;          // ushort offset of packed-h region
// h planes: packed uint32 (hi<<16 | lo), plane idx = which(0=h0,1=h1)*2 + parity
constexpr size_t HP_SZU  = 512ull * 256;         // uints per h plane
// sync area (uints, after 4 h planes), 128B-padded per strip:
//   cnt[mt]  @ SY + mt*32        (main step flags)
//   rdy[mt]  @ SY + 512 + mt*32  (handshake ready counters)
//   xct[mt,r]@ SY + 1024 + mt*32 + r   (XCC id exchange)
constexpr int SY_TOT = 2048;
constexpr unsigned STRIP = 12;
constexpr unsigned SPIN_MAIN = 1u << 16;   // valve: terminate visibly, never hang
constexpr unsigned SPIN_HAND = 1u << 16;

__device__ __forceinline__ float fsig(float v)  { return 1.0f / (1.0f + __expf(-v)); }
__device__ __forceinline__ float ftanh(float v) { return 2.0f / (1.0f + __expf(-2.0f * v)) - 1.0f; }

__device__ __forceinline__ void split1(float x, ushort_t& hi, ushort_t& lo) {
    unsigned u = __float_as_uint(x);
    hi = (ushort_t)(u >> 16);
    float r = x - __uint_as_float(u & 0xffff0000u);
    lo = (ushort_t)(__float_as_uint(r) >> 16);
}

// packed h element: top 16 bits = bf16(hi), low 16 bits = bf16(residual)
__device__ __forceinline__ uint_t packsplit(float x) {
    unsigned u = __float_as_uint(x);
    unsigned hib = u & 0xffff0000u;
    float r = x - __uint_as_float(hib);
    return hib | (__float_as_uint(r) >> 16);
}

__device__ __forceinline__ float lds_h(const ushort_t* hi, const ushort_t* lo, int idx) {
    return __uint_as_float(((unsigned)hi[idx]) << 16) + __uint_as_float(((unsigned)lo[idx]) << 16);
}

// ---------------- weight pre-pack (+ sync-area zeroing) ----------------
__global__ __launch_bounds__(256) void prep_pack(const float* __restrict__ Whh0,
                                                 const float* __restrict__ Wih1,
                                                 const float* __restrict__ Whh1,
                                                 ushort_t* __restrict__ PW) {
    const int blk = blockIdx.x;            // 144 = mat(3) x g(3) x jb(16)
    const int tid = threadIdx.x;

    // zero flags + handshake tables each launch (kills cross-run staleness)
    if (blk == 0) {
        uint_t* SY = (uint_t*)(PW + US_H) + 4 * HP_SZU;
        for (int u = tid; u < SY_TOT; u += 256)
            __hip_atomic_store(SY + u, 0u, __ATOMIC_RELAXED, __HIP_MEMORY_SCOPE_AGENT);
    }

    const int mat = blk / 48;
    const int rem = blk % 48;
    const int g   = rem / 16;
    const int jb  = rem % 16;
    const float* S = (mat == 0) ? Whh0 : (mat == 1) ? Wih1 : Whh1;

    const int jl  = tid >> 4;
    const int kc  = tid & 15;
    const int j   = jb * 16 + jl;
    const int nt  = jb * 3 + g;

    const float* src = S + (g * 256 + j) * 256 + kc * 16;
    float f[16];
#pragma unroll
    for (int q = 0; q < 4; q++) {
        float4 v = *(const float4*)(src + q * 4);
        f[q*4+0] = v.x; f[q*4+1] = v.y; f[q*4+2] = v.z; f[q*4+3] = v.w;
    }
    ushort_t hi[16], lo[16];
#pragma unroll
    for (int e = 0; e < 16; e++) split1(f[e], hi[e], lo[e]);

    ushort_t* dhi = PW + (size_t)(mat * 2 + 0) * PLANE_U;
    ushort_t* dlo = PW + (size_t)(mat * 2 + 1) * PLANE_U;
    const int ks = kc >> 1;
#pragma unroll
    for (int hh = 0; hh < 2; hh++) {
        const int quad = (kc & 1) * 2 + hh;
        const int L    = quad * 16 + jl;
        const size_t base = ((size_t)(nt * 8 + ks)) * 512 + L * 8;
        short8 vh, vl;
#pragma unroll
        for (int e = 0; e < 8; e++) { vh[e] = (short)hi[hh*8+e]; vl[e] = (short)lo[hh*8+e]; }
        *(short8*)(dhi + base) = vh;
        *(short8*)(dlo + base) = vl;
    }
}

// ---------------- staging: batch-issue 16B loads, then commit to LDS ----------------
// FAST: sc0 (L1-bypass) loads hit the XCD-shared L2 where producers' plain
//       write-back stores land (same-XCD verified by handshake).
// SLOW: device-scope intrinsic loads (coherence point).
template<bool FAST>
__device__ __forceinline__ void stage_issue(const uint_t* __restrict__ g, uintx4 (&v)[8], int tid) {
    const int c0 = (tid & 63) * 4;
    const int r0 = tid >> 6;
#pragma unroll
    for (int rr = 0; rr < 8; rr++) {
        const uint_t* p = g + (r0 + rr * 4) * 256 + c0;
        if (FAST) {
            // "=&v" earlyclobber: output must NOT alias the address pair
            asm volatile("global_load_dwordx4 %0, %1, off sc0"
                         : "=&v"(v[rr]) : "v"(p));
        } else {
            ull_t q0 = __hip_atomic_load((const ull_t*)(p),
                                         __ATOMIC_RELAXED, __HIP_MEMORY_SCOPE_AGENT);
            ull_t q1 = __hip_atomic_load((const ull_t*)(p + 2),
                                         __ATOMIC_RELAXED, __HIP_MEMORY_SCOPE_AGENT);
            v[rr][0] = (uint_t)q0; v[rr][1] = (uint_t)(q0 >> 32);
            v[rr][2] = (uint_t)q1; v[rr][3] = (uint_t)(q1 >> 32);
        }
    }
    if (FAST) {
        asm volatile("s_waitcnt vmcnt(0)" ::: "memory");
        __builtin_amdgcn_sched_barrier(0);
    }
}

__device__ __forceinline__ void stage_commit(const uintx4 (&v)[8], ushort_t* s_hi, ushort_t* s_lo, int tid) {
    const int c0 = (tid & 63) * 4;
    const int r0 = tid >> 6;
#pragma unroll
    for (int rr = 0; rr < 8; rr++) {
        const int row = r0 + rr * 4;
        const uint_t u0 = v[rr][0], u1 = v[rr][1], u2 = v[rr][2], u3 = v[rr][3];
        uint2 hv, lv;
        hv.x = (u0 >> 16) | (u1 & 0xffff0000u);
        hv.y = (u2 >> 16) | (u3 & 0xffff0000u);
        lv.x = (u0 & 0xffffu) | (u1 << 16);
        lv.y = (u2 & 0xffffu) | (u3 << 16);
        *(uint2*)(s_hi + row * 264 + c0) = hv;
        *(uint2*)(s_lo + row * 264 + c0) = lv;
    }
}

template<bool FAST>
__device__ __forceinline__ void st_h(uint_t* p, uint_t val) {
    if (FAST) {
        *p = val;   // write-back: lands in this XCD's L2 (L1 is write-through)
    } else {
        __hip_atomic_store(p, val, __ATOMIC_RELAXED, __HIP_MEMORY_SCOPE_AGENT);
    }
}

// Flag ops: ALWAYS compiler intrinsics (proven visible in rounds 1/3; the
// round-3 asm flag path never observed updates -> valve-paced 4 ms/step).
__device__ __forceinline__ uint_t ld_flag(const uint_t* p) {
    return __hip_atomic_load(p, __ATOMIC_RELAXED, __HIP_MEMORY_SCOPE_AGENT);
}

// Called by tid 0 AFTER __syncthreads(): every wave already drained its
// stores (vmcnt(0) before s_barrier), so RELAXED suffices — no release
// fence, no buffer_wbl2 L2 walk (round-1's killer).
__device__ __forceinline__ void publish(uint_t* cme) {
    __hip_atomic_fetch_add(cme, 1u, __ATOMIC_RELAXED, __HIP_MEMORY_SCOPE_AGENT);
}

// 3 N-tiles x full K=256, 3-pass split-bf16, two M-tiles sharing B regs.
__device__ __forceinline__ void wave_gemm(const ushort_t* sh_hi, const ushort_t* sh_lo,
                                          const ushort_t* __restrict__ bh_base,
                                          const ushort_t* __restrict__ bl_base,
                                          int jbg, int lane, floatx4 acc[3][2]) {
    const int m = lane & 15, quad = lane >> 4;
    const int aoff = m * 264 + quad * 8;
#pragma unroll
    for (int ks = 0; ks < 8; ks++) {
        short8 a0h = *(const short8*)(sh_hi + aoff + ks * 32);
        short8 a0l = *(const short8*)(sh_lo + aoff + ks * 32);
        short8 a1h = *(const short8*)(sh_hi + aoff + 16 * 264 + ks * 32);
        short8 a1l = *(const short8*)(sh_lo + aoff + 16 * 264 + ks * 32);
#pragma unroll
        for (int g = 0; g < 3; g++) {
            const size_t boff = (size_t)(jbg * 3 + g) * 4096 + (size_t)ks * 512 + lane * 8;
            short8 bh = *(const short8*)(bh_base + boff);
            short8 bl = *(const short8*)(bl_base + boff);
            acc[g][0] = __builtin_amdgcn_mfma_f32_16x16x32_bf16(a0h, bh, acc[g][0], 0, 0, 0);
            acc[g][0] = __builtin_amdgcn_mfma_f32_16x16x32_bf16(a0l, bh, acc[g][0], 0, 0, 0);
            acc[g][0] = __builtin_amdgcn_mfma_f32_16x16x32_bf16(a0h, bl, acc[g][0], 0, 0, 0);
            acc[g][1] = __builtin_amdgcn_mfma_f32_16x16x32_bf16(a1h, bh, acc[g][1], 0, 0, 0);
            acc[g][1] = __builtin_amdgcn_mfma_f32_16x16x32_bf16(a1l, bh, acc[g][1], 0, 0, 0);
            acc[g][1] = __builtin_amdgcn_mfma_f32_16x16x32_bf16(a1h, bl, acc[g][1], 0, 0, 0);
        }
    }
}

// ---------------- the persistent T-loop (templated on data-path mode) ----------------
template<bool FAST>
__device__ __forceinline__ void gru_loop(
    const float* __restrict__ x,
    const float* __restrict__ Wih0,
    const float* __restrict__ bih0, const float* __restrict__ bhh0,
    const float* __restrict__ bih1, const float* __restrict__ bhh1,
    ushort_t* __restrict__ WS,
    int mt, int ng, bool isL0, int tid,
    ushort_t* shA_hi, ushort_t* shA_lo, ushort_t* shB_hi, ushort_t* shB_lo,
    float (*xs)[C_IN], float (*ldH)[3][32][17])
{
    const int lane = tid & 63;
    const int w    = tid >> 6;
    const int jlo  = lane & 15;
    const int quad = lane >> 4;
    const int b0   = mt * 32;

    uint_t* const hU  = (uint_t*)(WS + US_H);
    uint_t* const cme = hU + 4 * HP_SZU + mt * 32;

    const int jbg0  = ng * 4 + w;        // L0 wave's jbg
    const int mat   = w >> 1;            // L1: 0 = Wih1 x h0, 1 = Whh1 x h1
    const int jbsub = w & 1;
    const int jbg1  = ng * 2 + jbsub;

    // ---- loop-invariant hoists ----
    float wxr[C_IN], wxz[C_IN], wxn[C_IN];
    float b_r = 0.f, b_z = 0.f, b_in = 0.f, b_hn = 0.f;
    if (isL0) {
        const int j = jbg0 * 16 + jlo;
#pragma unroll
        for (int i = 0; i < C_IN; i++) {
            wxr[i] = Wih0[j * C_IN + i];
            wxz[i] = Wih0[(256 + j) * C_IN + i];
            wxn[i] = Wih0[(512 + j) * C_IN + i];
        }
        b_r  = bih0[j] + bhh0[j];
        b_z  = bih0[256 + j] + bhh0[256 + j];
        b_in = bih0[512 + j];
        b_hn = bhh0[512 + j];
    } else if (mat == 0) {
        const int j = jbg1 * 16 + jlo;
        b_r  = bih1[j] + bhh1[j];
        b_z  = bih1[256 + j] + bhh1[256 + j];
        b_in = bih1[512 + j];
        b_hn = bhh1[512 + j];
    }
    const int rA = tid / C_IN, cA = tid - rA * C_IN;
    const int uB = tid + 256;
    const int rB = uB / C_IN, cB = uB - rB * C_IN;
    const int xoffA = (b0 + rA) * (C_T * C_IN) + cA;
    const int xoffB = (b0 + rB) * (C_T * C_IN) + cB;

#pragma unroll 1
    for (int k = 0; k <= C_T; ++k) {
        const int srcp = (k + 1) & 1, dstp = k & 1;
        const bool do_l0 = isL0 && (k < C_T);
        const bool l0z   = (k == 0);
        const bool do_l1 = (!isL0) && (k >= 1);
        const bool l1z   = (k == 1);

        // x prefetch (read-only input, normal cached load; in flight across the spin)
        float xa = 0.f, xb = 0.f;
        if (do_l0) {
            xa = x[xoffA + k * C_IN];
            if (tid < 64) xb = x[xoffB + k * C_IN];
        }

        // per-wave spin on the intrinsic flag (coherence-point atomic load)
        if (k > 0) {
            const uint_t tgt = STRIP * (uint_t)k;
            uint_t it = 0;
            while (ld_flag(cme) < tgt) {
                if (++it > SPIN_MAIN) break;   // valve: wrong-but-terminating
                __builtin_amdgcn_s_sleep(1);
            }
        }

        if (isL0) {
            if (do_l0) {
                xs[rA][cA] = xa;
                if (tid < 64) xs[rB][cB] = xb;
                if (!l0z) {
                    uintx4 va[8];
                    const uint_t* h0sb = hU + (size_t)srcp * HP_SZU + b0 * 256;
                    stage_issue<FAST>(h0sb, va, tid);
                    stage_commit(va, shA_hi, shA_lo, tid);
                }
                __syncthreads();

                floatx4 acc[3][2];
#pragma unroll
                for (int g = 0; g < 3; g++) { acc[g][0] = (floatx4){0,0,0,0}; acc[g][1] = (floatx4){0,0,0,0}; }
                if (!l0z)
                    wave_gemm(shA_hi, shA_lo, WS, WS + PLANE_U, jbg0, lane, acc);

                uint_t* const h0d = hU + (size_t)dstp * HP_SZU;
                const int j = jbg0 * 16 + jlo;
#pragma unroll
                for (int m = 0; m < 2; m++) {
#pragma unroll
                    for (int r = 0; r < 4; r++) {
                        const int row = m * 16 + quad * 4 + r;
                        float xrv = 0.f, xzv = 0.f, xnv = 0.f;
#pragma unroll
                        for (int i = 0; i < C_IN; i++) {
                            const float xv = xs[row][i];
                            xrv += xv * wxr[i]; xzv += xv * wxz[i]; xnv += xv * wxn[i];
                        }
                        const int gi = (b0 + row) * C_H + j;
                        // h_prev from the staged LDS tile (identical hi+lo reconstruction)
                        const float hp = l0z ? 0.f : lds_h(shA_hi, shA_lo, row * 264 + j);
                        const float ar  = acc[0][m][r] + xrv + b_r;
                        const float az  = acc[1][m][r] + xzv + b_z;
                        const float inn = xnv + b_in;
                        const float hn  = acc[2][m][r] + b_hn;
                        const float rg = fsig(ar), zg = fsig(az);
                        const float nn = ftanh(inn + rg * hn);
                        st_h<FAST>(h0d + gi, packsplit(zg * (hp - nn) + nn));
                    }
                }
            }
        } else {
            if (do_l1) {
                uintx4 va[8], vb[8];
                const uint_t* h0sb = hU + (size_t)srcp * HP_SZU + b0 * 256;
                const uint_t* h1sb = hU + (size_t)(2 + srcp) * HP_SZU + b0 * 256;
                stage_issue<FAST>(h0sb, va, tid);
                stage_commit(va, shA_hi, shA_lo, tid);
                if (!l1z) {
                    stage_issue<FAST>(h1sb, vb, tid);
                    stage_commit(vb, shB_hi, shB_lo, tid);
                }
                __syncthreads();

                floatx4 acc[3][2];
#pragma unroll
                for (int g = 0; g < 3; g++) { acc[g][0] = (floatx4){0,0,0,0}; acc[g][1] = (floatx4){0,0,0,0}; }
                if (mat == 0)
                    wave_gemm(shA_hi, shA_lo, WS + 2 * PLANE_U, WS + 3 * PLANE_U, jbg1, lane, acc);
                else if (!l1z)
                    wave_gemm(shB_hi, shB_lo, WS + 4 * PLANE_U, WS + 5 * PLANE_U, jbg1, lane, acc);

                if (mat == 1) {
#pragma unroll
                    for (int g = 0; g < 3; g++)
#pragma unroll
                        for (int m = 0; m < 2; m++)
#pragma unroll
                            for (int r = 0; r < 4; r++)
                                ldH[jbsub][g][m * 16 + quad * 4 + r][jlo] = acc[g][m][r];
                }
                __syncthreads();

                if (mat == 0) {
                    const int j = jbg1 * 16 + jlo;
                    uint_t* const h1d = hU + (size_t)(2 + dstp) * HP_SZU;
#pragma unroll
                    for (int m = 0; m < 2; m++) {
#pragma unroll
                        for (int r = 0; r < 4; r++) {
                            const int row = m * 16 + quad * 4 + r;
                            const int gi = (b0 + row) * C_H + j;
                            const float hp = l1z ? 0.f : lds_h(shB_hi, shB_lo, row * 264 + j);
                            const float ar  = acc[0][m][r] + ldH[jbsub][0][row][jlo] + b_r;
                            const float az  = acc[1][m][r] + ldH[jbsub][1][row][jlo] + b_z;
                            const float inn = acc[2][m][r] + b_in;
                            const float hn  = ldH[jbsub][2][row][jlo] + b_hn;
                            const float rg = fsig(ar), zg = fsig(az);
                            const float nn = ftanh(inn + rg * hn);
                            st_h<FAST>(h1d + gi, packsplit(zg * (hp - nn) + nn));
                        }
                    }
                }
            }
        }

        // barrier drains all waves' stores (compiler emits vmcnt(0) before
        // s_barrier); then one relaxed coherence-point add publishes the step.
        __syncthreads();
        if (tid == 0) publish(cme);
    }
}

__global__ __launch_bounds__(256) void gru_persistent(
    const float* __restrict__ x,
    const float* __restrict__ Wih0,
    const float* __restrict__ bih0, const float* __restrict__ bhh0,
    const float* __restrict__ bih1, const float* __restrict__ bhh1,
    ushort_t* __restrict__ WS)
{
    __shared__ __align__(16) ushort_t shA_hi[32 * 264], shA_lo[32 * 264];
    __shared__ __align__(16) ushort_t shB_hi[32 * 264], shB_lo[32 * 264];
    __shared__ float xs[32][C_IN];
    __shared__ float ldH[2][3][32][17];
    __shared__ int fastFlag;

    const int tid = threadIdx.x;
    const int bid = blockIdx.x;
    // strip-major mapping: all 12 blocks of strip mt share bid%8 (same XCD
    // under round-robin placement). Verified at runtime below; never assumed.
    const int slot = bid >> 3;                 // 0..23
    const int mt   = (bid & 7) + ((slot >= 12) ? 8 : 0);
    const int role = (slot >= 12) ? slot - 12 : slot;   // 0..11
    const bool isL0 = role < 4;
    const int ng = isL0 ? role : role - 4;

    uint_t* const hU  = (uint_t*)(WS + US_H);
    uint_t* const SY  = hU + 4 * HP_SZU;
    uint_t* const rdy = SY + 512 + mt * 32;
    uint_t* const xct = SY + 1024 + mt * 32;

    // ---- runtime coherence handshake (device-scope intrinsics only).
    // All 12 blocks read the SAME sc1 data -> all compute the SAME verdict:
    // mixed FAST/SLOW within a strip is impossible by construction.
    if (tid == 0) {
        uint_t xcc;
        asm volatile("s_getreg_b32 %0, hwreg(HW_REG_XCC_ID)" : "=s"(xcc));
        __hip_atomic_store(xct + role, xcc | 0x100u, __ATOMIC_RELAXED, __HIP_MEMORY_SCOPE_AGENT);
        // RELEASE: xct store globally visible before rdy increment (once per block)
        __hip_atomic_fetch_add(rdy, 1u, __ATOMIC_RELEASE, __HIP_MEMORY_SCOPE_AGENT);
        uint_t it = 0;
        while (__hip_atomic_load(rdy, __ATOMIC_RELAXED, __HIP_MEMORY_SCOPE_AGENT) < STRIP) {
            if (++it > SPIN_HAND) break;
            __builtin_amdgcn_s_sleep(8);
        }
        int ok = 1;
        const uint_t me = xcc | 0x100u;
        for (int r2 = 0; r2 < 12; r2++) {
            uint_t v = __hip_atomic_load(xct + r2, __ATOMIC_RELAXED, __HIP_MEMORY_SCOPE_AGENT);
            if (v != me) ok = 0;   // unset (0) or different XCD -> fallback
        }
        fastFlag = ok;
    }
    __syncthreads();
    const bool fast = (fastFlag != 0);

    if (fast)
        gru_loop<true >(x, Wih0, bih0, bhh0, bih1, bhh1, WS, mt, ng, isL0, tid,
                        shA_hi, shA_lo, shB_hi, shB_lo, xs, ldH);
    else
        gru_loop<false>(x, Wih0, bih0, bhh0, bih1, bhh1, WS, mt, ng, isL0, tid,
                        shA_hi, shA_lo, shB_hi, shB_lo, xs, ldH);
}

__global__ __launch_bounds__(256) void classifier_kernel(
    const ushort_t* __restrict__ WS,
    const float* __restrict__ Wout, const float* __restrict__ bout,
    float* __restrict__ out)
{
    __shared__ float hs[32][C_H + 4];
    __shared__ float lg[32 * C_OUT];
    const int tid = threadIdx.x;
    const int b0  = blockIdx.x * 32;
    // final h1 written at k=365 -> parity 1 -> plane index 2+1 = 3
    // (cross-dispatch visibility: end-of-kernel release + stream order)
    const uint_t* hp1 = (const uint_t*)(WS + US_H) + 3 * HP_SZU;
#pragma unroll
    for (int i = 0; i < 32; i++) {
        uint_t u = hp1[(b0 + i) * C_H + tid];
        hs[i][tid] = __uint_as_float(u & 0xffff0000u) + __uint_as_float(u << 16);
    }
    __syncthreads();
    for (int u = tid; u < 32 * C_OUT; u += 256) {
        int bb = u / C_OUT, o = u - bb * C_OUT;
        const float* wr = Wout + o * C_H;
        float acc = bout[o];
#pragma unroll 4
        for (int k = 0; k < C_H; k += 4) {
            float4 wv = *(const float4*)(wr + k);
            float4 hv = *(const float4*)(&hs[bb][k]);
            acc += wv.x*hv.x + wv.y*hv.y + wv.z*hv.z + wv.w*hv.w;
        }
        lg[u] = acc;
    }
    __syncthreads();
    if (tid < 32) {
        float mx = -1e30f;
#pragma unroll
        for (int o = 0; o < C_OUT; o++) mx = fmaxf(mx, lg[tid * C_OUT + o]);
        float e[C_OUT];
        float s = 0.0f;
#pragma unroll
        for (int o = 0; o < C_OUT; o++) { e[o] = __expf(lg[tid * C_OUT + o] - mx); s += e[o]; }
        float inv = 1.0f / s;
#pragma unroll
        for (int o = 0; o < C_OUT; o++) out[(b0 + tid) * C_OUT + o] = e[o] * inv;
    }
}

extern "C" void kernel_launch(void* const* d_in, const int* in_sizes, int n_in,
                              void* d_out, int out_size, void* d_ws, size_t ws_size,
                              hipStream_t stream) {
    const float* x    = (const float*)d_in[0];
    // d_in[1] = times (unused), d_in[2] = interpolation_method (unused)
    const float* Wih0 = (const float*)d_in[3];
    const float* Whh0 = (const float*)d_in[4];
    const float* bih0 = (const float*)d_in[5];
    const float* bhh0 = (const float*)d_in[6];
    const float* Wih1 = (const float*)d_in[7];
    const float* Whh1 = (const float*)d_in[8];
    const float* bih1 = (const float*)d_in[9];
    const float* bhh1 = (const float*)d_in[10];
    const float* Wout = (const float*)d_in[11];
    const float* bout = (const float*)d_in[12];
    float* out = (float*)d_out;
    ushort_t* WS = (ushort_t*)d_ws;

    // pack weights + zero sync area
    prep_pack<<<144, 256, 0, stream>>>(Whh0, Wih1, Whh1, WS);
    // whole recurrence in ONE dispatch (replaces 366 launches)
    gru_persistent<<<NB, 256, 0, stream>>>(x, Wih0, bih0, bhh0, bih1, bhh1, WS);
    classifier_kernel<<<C_B / 32, 256, 0, stream>>>(WS, Wout, bout, out);
}